// Round 7
// baseline (546.681 us; speedup 1.0000x reference)
//
#include <hip/hip_runtime.h>
#include <hip/hip_bf16.h>
#include <cstddef>

// Problem constants (EmbeddingEngine_47029891891415)
#define S_ 4
#define N_ 65536
#define K_ 64
#define D_ 256
#define P_ 8192

typedef __bf16 bf16x8 __attribute__((ext_vector_type(8)));
typedef float  f32x4  __attribute__((ext_vector_type(4)));

// Pack W [S][K=64][D=256] fp32 -> bf16 MFMA fragments in ws.
// wpack[(((s*2 + t)*16 + c)*64 + lane)*8 + i] =
//     bf16(W[s][t*32 + 8*(lane>>4) + i][c*16 + (lane&15)])
__global__ __launch_bounds__(256) void pack_w_kernel(const float* __restrict__ W,
                                                     __bf16* __restrict__ wpack) {
    int tid  = blockIdx.x * 256 + threadIdx.x;   // 0..65535
    int i    =  tid        & 7;
    int lane = (tid >> 3)  & 63;
    int c    = (tid >> 9)  & 15;
    int t    = (tid >> 13) & 1;
    int s    =  tid >> 14;
    int k    = t * 32 + 8 * (lane >> 4) + i;
    int col  = c * 16 + (lane & 15);
    wpack[tid] = (__bf16)W[(s * K_ + k) * D_ + col];
}

// A/B/C DIAGNOSTIC ROUND (rep=2 so each variant surfaces in rocprof top-5).
// Variant A: NTSTORE=1, FRAGS=16  (R3 baseline)
// Variant B: NTSTORE=0, FRAGS=16  (isolates nontemporal-store write amplification)
// Variant C: NTSTORE=0, FRAGS=8   (2x blocks, half per-wave regs -> occupancy probe)
// All write identical values to out -> last writer wins, deterministic.
template<bool NTSTORE, int FRAGS>
__global__ __launch_bounds__(256) void embed_tpl(
        const float* __restrict__ tokens,    // [S][N][K] f32
        const float* __restrict__ bvec,      // [S][D] f32
        const float* __restrict__ pe,        // [P][D] f32
        const int*   __restrict__ idxs,      // [S][N] i32
        const int*   __restrict__ idxs_pe,   // [S][N] i32
        const __bf16* __restrict__ wpack,    // packed W fragments (L2)
        float* __restrict__ out) {           // [S*N][D] f32
    constexpr int SPLIT = 16 / FRAGS;        // 1 or 2 blocks per 64-token tile
    const int blk   = blockIdx.x;
    const int half  = (SPLIT == 2) ? (blk & 1) : 0;
    const int tb    = (SPLIT == 2) ? (blk >> 1) : blk;
    const int s     = tb >> 10;              // 1024 tiles per stream
    const int tile  = tb & 1023;
    const int wave  = threadIdx.x >> 6;
    const int lane  = threadIdx.x & 63;
    const int j     = lane & 15;             // token within wave tile
    const int g     = lane >> 4;
    const int rowbase = tile * 64 + wave * 16;
    const int trowi   = rowbase + j;         // token row within stream
    const int cbase   = half * FRAGS;        // fragment (16-col block) offset

    for (int rep = 0; rep < 2; ++rep) {
        // ---- token B-fragments: tok[trowi][k], k = t*32 + 8g + e (streaming)
        const float* trow = tokens + ((size_t)s * N_ + trowi) * K_;
        f32x4 t0lo = __builtin_nontemporal_load((const f32x4*)(trow +      8 * g));
        f32x4 t0hi = __builtin_nontemporal_load((const f32x4*)(trow +      8 * g + 4));
        f32x4 t1lo = __builtin_nontemporal_load((const f32x4*)(trow + 32 + 8 * g));
        f32x4 t1hi = __builtin_nontemporal_load((const f32x4*)(trow + 32 + 8 * g + 4));
        bf16x8 a0, a1;
#pragma unroll
        for (int e = 0; e < 4; ++e) {
            a0[e]     = (__bf16)t0lo[e];
            a0[e + 4] = (__bf16)t0hi[e];
            a1[e]     = (__bf16)t1lo[e];
            a1[e + 4] = (__bf16)t1hi[e];
        }

        // ---- W fragments (L2-resident) + MFMA (swapped operands)
        const bf16x8* wp0 = (const bf16x8*)wpack + (size_t)((s * 2 + 0) * 16) * 64;
        const bf16x8* wp1 = (const bf16x8*)wpack + (size_t)((s * 2 + 1) * 16) * 64;

        f32x4 acc[FRAGS];
#pragma unroll
        for (int c = 0; c < FRAGS; ++c) acc[c] = (f32x4){0.f, 0.f, 0.f, 0.f};
#pragma unroll
        for (int c = 0; c < FRAGS; ++c) {
            bf16x8 w0 = wp0[(cbase + c) * 64 + lane];
            bf16x8 w1 = wp1[(cbase + c) * 64 + lane];
            acc[c] = __builtin_amdgcn_mfma_f32_16x16x32_bf16(w0, a0, acc[c], 0, 0, 0);
            acc[c] = __builtin_amdgcn_mfma_f32_16x16x32_bf16(w1, a1, acc[c], 0, 0, 0);
        }

        // ---- Epilogue: lane owns token trowi, d = (cbase+c)*16 + g*4 + {0..3}
        const int orow = idxs   [s * N_ + trowi];
        const int ipe  = idxs_pe[s * N_ + trowi];
        const float* __restrict__ perow = pe + (size_t)ipe * D_ + cbase * 16 + g * 4;
        const float* __restrict__ brow  = bvec + s * D_ + cbase * 16 + g * 4;
        float* __restrict__ optr        = out + (size_t)orow * D_ + cbase * 16 + g * 4;
#pragma unroll
        for (int c = 0; c < FRAGS; ++c) {
            f32x4 pev = *(const f32x4*)(perow + c * 16);
            f32x4 bbv = *(const f32x4*)(brow  + c * 16);
            f32x4 o   = acc[c] + bbv + pev;
            if constexpr (NTSTORE)
                __builtin_nontemporal_store(o, (f32x4*)(optr + c * 16));
            else
                *(f32x4*)(optr + c * 16) = o;
        }

        asm volatile("" ::: "memory");   // no CSE across reps
    }
}

extern "C" void kernel_launch(void* const* d_in, const int* in_sizes, int n_in,
                              void* d_out, int out_size, void* d_ws, size_t ws_size,
                              hipStream_t stream) {
    const float* tokens  = (const float*)d_in[0];
    const float* W       = (const float*)d_in[1];
    const float* bvec    = (const float*)d_in[2];
    const float* pe      = (const float*)d_in[3];
    const int*   idxs    = (const int*)d_in[4];
    const int*   idxs_pe = (const int*)d_in[5];
    float* out = (float*)d_out;
    __bf16* wpack = (__bf16*)d_ws;   // 128 KB

    pack_w_kernel<<<256, 256, 0, stream>>>(W, wpack);
    // A: R3 baseline (NT stores, 16 frags)
    embed_tpl<true, 16><<<4096, 256, 0, stream>>>(tokens, bvec, pe, idxs, idxs_pe, wpack, out);
    // B: plain stores (isolate NT write amplification)
    embed_tpl<false, 16><<<4096, 256, 0, stream>>>(tokens, bvec, pe, idxs, idxs_pe, wpack, out);
    // C: plain stores + half per-wave work, 2x blocks (occupancy probe)
    embed_tpl<false, 8><<<8192, 256, 0, stream>>>(tokens, bvec, pe, idxs, idxs_pe, wpack, out);
}

// Round 8
// 143.320 us; speedup vs baseline: 3.8144x; 3.8144x over previous
//
#include <hip/hip_runtime.h>
#include <hip/hip_bf16.h>
#include <cstddef>

// Problem constants (EmbeddingEngine_47029891891415)
#define S_ 4
#define N_ 65536
#define K_ 64
#define D_ 256
#define P_ 8192

typedef __bf16 bf16x8 __attribute__((ext_vector_type(8)));
typedef float  f32x4  __attribute__((ext_vector_type(4)));

// Pack W [S][K=64][D=256] fp32 -> bf16 MFMA fragments in ws.
// wpack[(((s*2 + t)*16 + c)*64 + lane)*8 + i] =
//     bf16(W[s][t*32 + 8*(lane>>4) + i][c*16 + (lane&15)])
// A-fragment lane mapping (i = lane&15, k = 8*(lane>>4)+e) equals the
// B-fragment mapping, so this pack serves the swapped-operand GEMM.
__global__ __launch_bounds__(256) void pack_w_kernel(const float* __restrict__ W,
                                                     __bf16* __restrict__ wpack) {
    int tid  = blockIdx.x * 256 + threadIdx.x;   // 0..65535
    int i    =  tid        & 7;
    int lane = (tid >> 3)  & 63;
    int c    = (tid >> 9)  & 15;
    int t    = (tid >> 13) & 1;
    int s    =  tid >> 14;
    int k    = t * 32 + 8 * (lane >> 4) + i;
    int col  = c * 16 + (lane & 15);
    wpack[tid] = (__bf16)W[(s * K_ + k) * D_ + col];
}

// Winner config from the R7 A/B/C probe: plain stores (NT stores cost ~50%
// on the store path), FRAGS=8 with 2 blocks per 64-token tile (halves
// per-wave VMEM/register footprint -> more latency hiding).
// One block = one stream s, one 64-token tile, one 128-col half.
// Swapped-operand MFMA: D[i=d_local][j=token_local] = sum_k W[k][d]*tok[j][k]
// C/D layout (m89/m91): col(lane&15)=token j, row(g*4+reg)=d_local
// -> each lane owns 4 consecutive d of one token.
__global__ __launch_bounds__(256) void embed_kernel(
        const float* __restrict__ tokens,    // [S][N][K] f32
        const float* __restrict__ bvec,      // [S][D] f32
        const float* __restrict__ pe,        // [P][D] f32
        const int*   __restrict__ idxs,      // [S][N] i32
        const int*   __restrict__ idxs_pe,   // [S][N] i32
        const __bf16* __restrict__ wpack,    // packed W fragments (L2)
        float* __restrict__ out) {           // [S*N][D] f32
    const int blk   = blockIdx.x;            // 0..8191
    const int half  = blk & 1;               // which 128-col half
    const int tb    = blk >> 1;
    const int s     = tb >> 10;              // 1024 tiles per stream
    const int tile  = tb & 1023;
    const int wave  = threadIdx.x >> 6;
    const int lane  = threadIdx.x & 63;
    const int j     = lane & 15;             // token within wave tile
    const int g     = lane >> 4;
    const int rowbase = tile * 64 + wave * 16;
    const int trowi   = rowbase + j;         // token row within stream
    const int cbase   = half * 8;            // fragment (16-col block) offset

    // ---- token B-fragments: tok[trowi][k], k = t*32 + 8g + e (streaming)
    const float* trow = tokens + ((size_t)s * N_ + trowi) * K_;
    f32x4 t0lo = __builtin_nontemporal_load((const f32x4*)(trow +      8 * g));
    f32x4 t0hi = __builtin_nontemporal_load((const f32x4*)(trow +      8 * g + 4));
    f32x4 t1lo = __builtin_nontemporal_load((const f32x4*)(trow + 32 + 8 * g));
    f32x4 t1hi = __builtin_nontemporal_load((const f32x4*)(trow + 32 + 8 * g + 4));
    bf16x8 a0, a1;
#pragma unroll
    for (int e = 0; e < 4; ++e) {
        a0[e]     = (__bf16)t0lo[e];
        a0[e + 4] = (__bf16)t0hi[e];
        a1[e]     = (__bf16)t1lo[e];
        a1[e + 4] = (__bf16)t1hi[e];
    }

    // ---- W fragments (L2-resident) + MFMA (swapped operands)
    const bf16x8* wp0 = (const bf16x8*)wpack + (size_t)((s * 2 + 0) * 16) * 64;
    const bf16x8* wp1 = (const bf16x8*)wpack + (size_t)((s * 2 + 1) * 16) * 64;

    f32x4 acc[8];
#pragma unroll
    for (int c = 0; c < 8; ++c) acc[c] = (f32x4){0.f, 0.f, 0.f, 0.f};
#pragma unroll
    for (int c = 0; c < 8; ++c) {
        bf16x8 w0 = wp0[(cbase + c) * 64 + lane];
        bf16x8 w1 = wp1[(cbase + c) * 64 + lane];
        acc[c] = __builtin_amdgcn_mfma_f32_16x16x32_bf16(w0, a0, acc[c], 0, 0, 0);
        acc[c] = __builtin_amdgcn_mfma_f32_16x16x32_bf16(w1, a1, acc[c], 0, 0, 0);
    }

    // ---- Epilogue: lane owns token trowi, d = (cbase+c)*16 + g*4 + {0..3}
    const int orow = idxs   [s * N_ + trowi];
    const int ipe  = idxs_pe[s * N_ + trowi];
    const float* __restrict__ perow = pe + (size_t)ipe * D_ + cbase * 16 + g * 4;
    const float* __restrict__ brow  = bvec + s * D_ + cbase * 16 + g * 4;
    float* __restrict__ optr        = out + (size_t)orow * D_ + cbase * 16 + g * 4;
#pragma unroll
    for (int c = 0; c < 8; ++c) {
        f32x4 pev = *(const f32x4*)(perow + c * 16);
        f32x4 bbv = *(const f32x4*)(brow  + c * 16);
        f32x4 o   = acc[c] + bbv + pev;
        *(f32x4*)(optr + c * 16) = o;   // plain store (A/B-proven vs NT)
    }
}

extern "C" void kernel_launch(void* const* d_in, const int* in_sizes, int n_in,
                              void* d_out, int out_size, void* d_ws, size_t ws_size,
                              hipStream_t stream) {
    const float* tokens  = (const float*)d_in[0];
    const float* W       = (const float*)d_in[1];
    const float* bvec    = (const float*)d_in[2];
    const float* pe      = (const float*)d_in[3];
    const int*   idxs    = (const int*)d_in[4];
    const int*   idxs_pe = (const int*)d_in[5];
    float* out = (float*)d_out;
    __bf16* wpack = (__bf16*)d_ws;   // 128 KB

    pack_w_kernel<<<256, 256, 0, stream>>>(W, wpack);
    embed_kernel<<<S_ * (N_ / 64) * 2, 256, 0, stream>>>(tokens, bvec, pe, idxs, idxs_pe,
                                                         wpack, out);
}

// Round 9
// 122.944 us; speedup vs baseline: 4.4466x; 1.1657x over previous
//
#include <hip/hip_runtime.h>
#include <hip/hip_bf16.h>
#include <cstddef>

// Problem constants (EmbeddingEngine_47029891891415)
#define S_ 4
#define N_ 65536
#define K_ 64
#define D_ 256
#define P_ 8192

typedef __bf16 bf16x8 __attribute__((ext_vector_type(8)));
typedef __bf16 bf16x4 __attribute__((ext_vector_type(4)));
typedef float  f32x4  __attribute__((ext_vector_type(4)));

// ws layout: [0, 128KB): wpack | [256KB, 256KB+4MB): pe_bf
#define PE_OFF_BYTES (256 * 1024)

// Prep. Blocks 0..255: pack W [S][64][256] f32 -> bf16 MFMA fragments:
//   wpack[(((s*2 + t)*16 + c)*64 + lane)*8 + i] =
//       bf16(W[s][t*32 + 8*(lane>>4) + i][c*16 + (lane&15)])
// Blocks 256..2303: pe f32 -> bf16 (4 elems/thread), plain stores (cache it).
__global__ __launch_bounds__(256) void prep_kernel(const float* __restrict__ W,
                                                   const float* __restrict__ pe,
                                                   __bf16* __restrict__ wpack,
                                                   __bf16* __restrict__ pe_bf) {
    const int b = blockIdx.x;
    if (b < 256) {
        int tid  = b * 256 + threadIdx.x;   // 0..65535
        int i    =  tid        & 7;
        int lane = (tid >> 3)  & 63;
        int c    = (tid >> 9)  & 15;
        int t    = (tid >> 13) & 1;
        int s    =  tid >> 14;
        int k    = t * 32 + 8 * (lane >> 4) + i;
        int col  = c * 16 + (lane & 15);
        wpack[tid] = (__bf16)W[(s * K_ + k) * D_ + col];
    } else {
        int t = (b - 256) * 256 + threadIdx.x;      // 0..524287
        f32x4 v = __builtin_nontemporal_load((const f32x4*)(pe + (size_t)t * 4));
        bf16x4 o;
        o[0] = (__bf16)v[0]; o[1] = (__bf16)v[1];
        o[2] = (__bf16)v[2]; o[3] = (__bf16)v[3];
        *(bf16x4*)(pe_bf + (size_t)t * 4) = o;
    }
}

// EXACTLY the R3 118us kernel except pe is gathered as bf16 from ws:
// halves gather bytes (268->134 MB logical) and the 4.2 MB table fits each
// XCD's 4 MB L2 -> random gathers become L2 hits instead of L3 traffic.
// Single lever vs R3; gathers stay in epilogue position (R4's hoist was the
// confound). Swapped-operand MFMA, C/D layout (m89/m91): col(lane&15)=token,
// row(g*4+reg)=d_local -> each lane owns 4 consecutive d of one token.
__global__ __launch_bounds__(256) void embed_kernel(
        const float* __restrict__ tokens,    // [S][N][K] f32
        const float* __restrict__ bvec,      // [S][D] f32
        const int*   __restrict__ idxs,      // [S][N] i32
        const int*   __restrict__ idxs_pe,   // [S][N] i32
        const __bf16* __restrict__ wpack,    // packed W fragments (L2)
        const __bf16* __restrict__ pe_bf,    // [P][D] bf16 (L2-resident)
        float* __restrict__ out) {           // [S*N][D] f32
    const int blk   = blockIdx.x;            // 0..4095
    const int s     = blk >> 10;             // 1024 tiles per stream
    const int tile  = blk & 1023;
    const int wave  = threadIdx.x >> 6;
    const int lane  = threadIdx.x & 63;
    const int j     = lane & 15;             // token within wave tile
    const int g     = lane >> 4;
    const int rowbase = tile * 64 + wave * 16;
    const int trowi   = rowbase + j;         // token row within stream

    // ---- token fragments: tok[trowi][k], k = t*32 + 8g + e (streaming)
    const float* trow = tokens + ((size_t)s * N_ + trowi) * K_;
    f32x4 t0lo = __builtin_nontemporal_load((const f32x4*)(trow +      8 * g));
    f32x4 t0hi = __builtin_nontemporal_load((const f32x4*)(trow +      8 * g + 4));
    f32x4 t1lo = __builtin_nontemporal_load((const f32x4*)(trow + 32 + 8 * g));
    f32x4 t1hi = __builtin_nontemporal_load((const f32x4*)(trow + 32 + 8 * g + 4));
    bf16x8 a0, a1;
#pragma unroll
    for (int e = 0; e < 4; ++e) {
        a0[e]     = (__bf16)t0lo[e];
        a0[e + 4] = (__bf16)t0hi[e];
        a1[e]     = (__bf16)t1lo[e];
        a1[e + 4] = (__bf16)t1hi[e];
    }

    // ---- W fragments (L2-resident) + MFMA (swapped operands)
    const bf16x8* wp0 = (const bf16x8*)wpack + (size_t)((s * 2 + 0) * 16) * 64;
    const bf16x8* wp1 = (const bf16x8*)wpack + (size_t)((s * 2 + 1) * 16) * 64;

    f32x4 acc[16];
#pragma unroll
    for (int c = 0; c < 16; ++c) acc[c] = (f32x4){0.f, 0.f, 0.f, 0.f};
#pragma unroll
    for (int c = 0; c < 16; ++c) {
        bf16x8 w0 = wp0[c * 64 + lane];
        bf16x8 w1 = wp1[c * 64 + lane];
        acc[c] = __builtin_amdgcn_mfma_f32_16x16x32_bf16(w0, a0, acc[c], 0, 0, 0);
        acc[c] = __builtin_amdgcn_mfma_f32_16x16x32_bf16(w1, a1, acc[c], 0, 0, 0);
    }

    // ---- Epilogue: lane owns token trowi, d = c*16 + g*4 + {0..3}
    const int orow = idxs   [s * N_ + trowi];
    const int ipe  = idxs_pe[s * N_ + trowi];
    const __bf16* __restrict__ perow = pe_bf + (size_t)ipe * D_ + g * 4;
    const float*  __restrict__ brow  = bvec + s * D_ + g * 4;
    float* __restrict__ optr         = out + (size_t)orow * D_ + g * 4;
#pragma unroll
    for (int c = 0; c < 16; ++c) {
        bf16x4 pev = *(const bf16x4*)(perow + c * 16);
        f32x4  bbv = *(const f32x4*)(brow + c * 16);
        f32x4  o;
#pragma unroll
        for (int e = 0; e < 4; ++e)
            o[e] = acc[c][e] + bbv[e] + (float)pev[e];
        __builtin_nontemporal_store(o, (f32x4*)(optr + c * 16));
    }
}

extern "C" void kernel_launch(void* const* d_in, const int* in_sizes, int n_in,
                              void* d_out, int out_size, void* d_ws, size_t ws_size,
                              hipStream_t stream) {
    const float* tokens  = (const float*)d_in[0];
    const float* W       = (const float*)d_in[1];
    const float* bvec    = (const float*)d_in[2];
    const float* pe      = (const float*)d_in[3];
    const int*   idxs    = (const int*)d_in[4];
    const int*   idxs_pe = (const int*)d_in[5];
    float* out = (float*)d_out;
    __bf16* wpack = (__bf16*)d_ws;
    __bf16* pe_bf = (__bf16*)((char*)d_ws + PE_OFF_BYTES);

    prep_kernel<<<256 + (P_ * D_ / 4 / 256), 256, 0, stream>>>(W, pe, wpack, pe_bf);
    embed_kernel<<<S_ * (N_ / 64), 256, 0, stream>>>(tokens, bvec, idxs, idxs_pe,
                                                     wpack, pe_bf, out);
}

// Round 10
// 107.320 us; speedup vs baseline: 5.0939x; 1.1456x over previous
//
#include <hip/hip_runtime.h>
#include <hip/hip_bf16.h>
#include <cstddef>

// Problem constants (EmbeddingEngine_47029891891415)
#define S_ 4
#define N_ 65536
#define K_ 64
#define D_ 256
#define P_ 8192

typedef __bf16 bf16x8 __attribute__((ext_vector_type(8)));
typedef float  f32x4  __attribute__((ext_vector_type(4)));

// Pack W [S][K=64][D=256] fp32 -> bf16 MFMA fragments in ws.
// wpack[(((s*2 + t)*16 + c)*64 + lane)*8 + i] =
//     bf16(W[s][t*32 + 8*(lane>>4) + i][c*16 + (lane&15)])
__global__ __launch_bounds__(256) void pack_w_kernel(const float* __restrict__ W,
                                                     __bf16* __restrict__ wpack) {
    int tid  = blockIdx.x * 256 + threadIdx.x;   // 0..65535
    int i    =  tid        & 7;
    int lane = (tid >> 3)  & 63;
    int c    = (tid >> 9)  & 15;
    int t    = (tid >> 13) & 1;
    int s    =  tid >> 14;
    int k    = t * 32 + 8 * (lane >> 4) + i;
    int col  = c * 16 + (lane & 15);
    wpack[tid] = (__bf16)W[(s * K_ + k) * D_ + col];
}

// R3 base + LDS-transposed store epilogue (single lever vs R3).
// MFMA/C-layout unchanged: lane (j=lane&15, g=lane>>4) owns token rowbase+j,
// d = c*16 + g*4 + {0..3}. Instead of storing that column-fragment pattern
// (16 rows x 64B per instruction, gather->store ping-pong), each wave stages
// o[c] into a wave-private LDS tile [16][136] and re-emits stores as
// CONTIGUOUS half-rows: lanes 0..31 = 512B consecutive of one row, 16
// back-to-back store instructions per pass, no loads interleaved
// (fillBuffer-like write stream). Two passes of 8 fragments keep LDS at
// 4 waves x 16 x 136 floats = 34 KB/block. No __syncthreads: LDS regions are
// wave-private, in-wave ds ordering via lgkmcnt (compiler-inserted).
__global__ __launch_bounds__(256) void embed_kernel(
        const float* __restrict__ tokens,    // [S][N][K] f32
        const float* __restrict__ bvec,      // [S][D] f32
        const float* __restrict__ pe,        // [P][D] f32
        const int*   __restrict__ idxs,      // [S][N] i32
        const int*   __restrict__ idxs_pe,   // [S][N] i32
        const __bf16* __restrict__ wpack,    // packed W fragments (L2)
        float* __restrict__ out) {           // [S*N][D] f32
    const int blk   = blockIdx.x;            // 0..4095
    const int s     = blk >> 10;             // 1024 tiles per stream
    const int tile  = blk & 1023;
    const int wave  = threadIdx.x >> 6;
    const int lane  = threadIdx.x & 63;
    const int j     = lane & 15;             // token within wave tile
    const int g     = lane >> 4;
    const int rowbase = tile * 64 + wave * 16;
    const int trowi   = rowbase + j;         // token row within stream

    __shared__ float lds[4][16][136];        // per-wave [row][128+8 pad]
    float* const wl = &lds[wave][0][0];

    // ---- token fragments: tok[trowi][k], k = t*32 + 8g + e (streaming)
    const float* trow = tokens + ((size_t)s * N_ + trowi) * K_;
    f32x4 t0lo = __builtin_nontemporal_load((const f32x4*)(trow +      8 * g));
    f32x4 t0hi = __builtin_nontemporal_load((const f32x4*)(trow +      8 * g + 4));
    f32x4 t1lo = __builtin_nontemporal_load((const f32x4*)(trow + 32 + 8 * g));
    f32x4 t1hi = __builtin_nontemporal_load((const f32x4*)(trow + 32 + 8 * g + 4));
    bf16x8 a0, a1;
#pragma unroll
    for (int e = 0; e < 4; ++e) {
        a0[e]     = (__bf16)t0lo[e];
        a0[e + 4] = (__bf16)t0hi[e];
        a1[e]     = (__bf16)t1lo[e];
        a1[e + 4] = (__bf16)t1hi[e];
    }

    // ---- W fragments (L2-resident) + MFMA (swapped operands)
    const bf16x8* wp0 = (const bf16x8*)wpack + (size_t)((s * 2 + 0) * 16) * 64;
    const bf16x8* wp1 = (const bf16x8*)wpack + (size_t)((s * 2 + 1) * 16) * 64;

    f32x4 acc[16];
#pragma unroll
    for (int c = 0; c < 16; ++c) acc[c] = (f32x4){0.f, 0.f, 0.f, 0.f};
#pragma unroll
    for (int c = 0; c < 16; ++c) {
        bf16x8 w0 = wp0[c * 64 + lane];
        bf16x8 w1 = wp1[c * 64 + lane];
        acc[c] = __builtin_amdgcn_mfma_f32_16x16x32_bf16(w0, a0, acc[c], 0, 0, 0);
        acc[c] = __builtin_amdgcn_mfma_f32_16x16x32_bf16(w1, a1, acc[c], 0, 0, 0);
    }

    // ---- Epilogue
    const int ipe  = idxs_pe[s * N_ + trowi];
    const float* __restrict__ perow = pe + (size_t)ipe * D_ + g * 4;
    const float* __restrict__ brow  = bvec + s * D_ + g * 4;
    const int   hi = lane >> 5;              // row parity for store phase
    const int   lo = lane & 31;              // 32-lane half-row cover

#pragma unroll
    for (int p = 0; p < 2; ++p) {
        // Phase 1: gather pe + add, stage fragment into LDS (wave-private)
#pragma unroll
        for (int cc = 0; cc < 8; ++cc) {
            const int c = p * 8 + cc;
            f32x4 pev = *(const f32x4*)(perow + c * 16);
            f32x4 bbv = *(const f32x4*)(brow  + c * 16);
            f32x4 o   = acc[c] + bbv + pev;
            *(f32x4*)(wl + j * 136 + cc * 16 + g * 4) = o;
        }
        // Phase 2: pure contiguous store burst — 2 rows x 512B per instr
#pragma unroll
        for (int rr = 0; rr < 8; ++rr) {
            const int r      = rr * 2 + hi;
            const int orow_r = idxs[s * N_ + rowbase + r];
            f32x4 v = *(const f32x4*)(wl + r * 136 + lo * 4);
            __builtin_nontemporal_store(
                v, (f32x4*)(out + (size_t)orow_r * D_ + p * 128 + lo * 4));
        }
    }
}

extern "C" void kernel_launch(void* const* d_in, const int* in_sizes, int n_in,
                              void* d_out, int out_size, void* d_ws, size_t ws_size,
                              hipStream_t stream) {
    const float* tokens  = (const float*)d_in[0];
    const float* W       = (const float*)d_in[1];
    const float* bvec    = (const float*)d_in[2];
    const float* pe      = (const float*)d_in[3];
    const int*   idxs    = (const int*)d_in[4];
    const int*   idxs_pe = (const int*)d_in[5];
    float* out = (float*)d_out;
    __bf16* wpack = (__bf16*)d_ws;   // 128 KB

    pack_w_kernel<<<256, 256, 0, stream>>>(W, wpack);
    embed_kernel<<<S_ * (N_ / 64), 256, 0, stream>>>(tokens, bvec, pe, idxs, idxs_pe,
                                                     wpack, out);
}